// Round 9
// baseline (286.027 us; speedup 1.0000x reference)
//
#include <hip/hip_runtime.h>
#include <hip/hip_cooperative_groups.h>
#include <math.h>

namespace cg = cooperative_groups;

#define BB 2
#define LL 1024
#define DD 512
#define DIN 1024      // d_inner
#define NS 16         // d_state
#define RNK 32        // dt_rank
#define ML (BB*LL)    // 2048 rows
#define CT 16         // scan chunk length
#define NC (LL/CT)    // 64 chunks
#define BDIN (BB*DIN) // 2048

typedef unsigned short u16;
typedef unsigned int u32;

__device__ __forceinline__ float sigmoidf_(float v) { return 1.f / (1.f + __expf(-v)); }
__device__ __forceinline__ float siluf_(float v) { return v * sigmoidf_(v); }
__device__ __forceinline__ u16 f2bf(float f) {
  union { float f; u32 u; } c; c.f = f;
  u32 r = c.u + 0x7fffu + ((c.u >> 16) & 1u);
  return (u16)(r >> 16);
}
__device__ __forceinline__ float bf2f(u16 x) {
  union { u32 u; float f; } c; c.u = (u32)x << 16;
  return c.f;
}

// ---------------- fused bf16 cast of x + all weights (one launch) ----------------
// 2048 elems/block: x 512 | W_in 512 | W_xp 32 | W_dt 16 | W_out 256 | W_ff1 256 | W_ff2 256
__global__ __launch_bounds__(256) void cast_all(const float* __restrict__ x,
                                                const float* __restrict__ Wi,
                                                const float* __restrict__ Wx,
                                                const float* __restrict__ Wd,
                                                const float* __restrict__ Wo,
                                                const float* __restrict__ Wf1,
                                                const float* __restrict__ Wf2,
                                                u16* bx, u16* bWi, u16* bWx, u16* bWd,
                                                u16* bWo, u16* bWf1, u16* bWf2)
{
  int bid = blockIdx.x;
  const float* src; u16* dst; int base;
  if (bid < 512)       { src = x;   dst = bx;   base = 0; }
  else if (bid < 1024) { src = Wi;  dst = bWi;  base = 512; }
  else if (bid < 1056) { src = Wx;  dst = bWx;  base = 1024; }
  else if (bid < 1072) { src = Wd;  dst = bWd;  base = 1056; }
  else if (bid < 1328) { src = Wo;  dst = bWo;  base = 1072; }
  else if (bid < 1584) { src = Wf1; dst = bWf1; base = 1328; }
  else                 { src = Wf2; dst = bWf2; base = 1584; }
  int i = ((bid - base) * 256 + threadIdx.x) * 8;
  float4 v0 = *(const float4*)&src[i];
  float4 v1 = *(const float4*)&src[i + 4];
  union { u16 u[8]; uint4 v; } p;
  p.u[0] = f2bf(v0.x); p.u[1] = f2bf(v0.y); p.u[2] = f2bf(v0.z); p.u[3] = f2bf(v0.w);
  p.u[4] = f2bf(v1.x); p.u[5] = f2bf(v1.y); p.u[6] = f2bf(v1.z); p.u[7] = f2bf(v1.w);
  *(uint4*)&dst[i] = p.v;
}

// ---------------- tiled bf16 MFMA GEMM: C[M,N] = A[M,K] @ W[N,K]^T ----------------
// EPI: 0 none, 1 +bias, 2 +bias+gelu, 3 +bias+softplus.  OT: float or u16
using bf16x8 = __attribute__((ext_vector_type(8))) short;
using f32x4  = __attribute__((ext_vector_type(4))) float;

template<int BM, int BN, int EPI, typename OT>
__global__ __launch_bounds__(256) void gemm_t(const u16* __restrict__ A,
                                              const u16* __restrict__ W,
                                              const float* __restrict__ bias,
                                              OT* __restrict__ C,
                                              int M, int N, int K)
{
  constexpr int WR = BM / 64;
  constexpr int WC = 4 / WR;
  constexpr int NW = BN / WC;       // cols per wave
  constexpr int JJ = NW / 16;       // 16-col fragments per wave
  constexpr int RB = BN / 64;       // B row-groups for staging
  __shared__ u16 As[BM][40];        // pad to 40 (80B row): 2-way bank alias = free
  __shared__ u16 Bs[BN][40];
  const int bm = blockIdx.y * BM, bn = blockIdx.x * BN;
  const int tid = threadIdx.x;
  const int w = tid >> 6, l = tid & 63;
  const int wr = w / WC, wc = w % WC;
  const int lr = l & 15, lh = l >> 4;
  const int sr0 = tid >> 2, sc0 = tid & 3;
  f32x4 acc[4][JJ] = {};
  for (int k0 = 0; k0 < K; k0 += 32) {
    uint4 areg[WR], breg[RB];
#pragma unroll
    for (int i = 0; i < WR; ++i)
      areg[i] = *(const uint4*)&A[(size_t)(bm + sr0 + 64 * i) * K + k0 + sc0 * 8];
#pragma unroll
    for (int i = 0; i < RB; ++i)
      breg[i] = *(const uint4*)&W[(size_t)(bn + sr0 + 64 * i) * K + k0 + sc0 * 8];
    __syncthreads();
#pragma unroll
    for (int i = 0; i < WR; ++i) *(uint4*)&As[sr0 + 64 * i][sc0 * 8] = areg[i];
#pragma unroll
    for (int i = 0; i < RB; ++i) *(uint4*)&Bs[sr0 + 64 * i][sc0 * 8] = breg[i];
    __syncthreads();
    bf16x8 af[4], bfr[JJ];
#pragma unroll
    for (int i = 0; i < 4; ++i) af[i]  = *(bf16x8*)&As[wr * 64 + i * 16 + lr][lh * 8];
#pragma unroll
    for (int j = 0; j < JJ; ++j) bfr[j] = *(bf16x8*)&Bs[wc * NW + j * 16 + lr][lh * 8];
#pragma unroll
    for (int i = 0; i < 4; ++i)
#pragma unroll
      for (int j = 0; j < JJ; ++j)
        acc[i][j] = __builtin_amdgcn_mfma_f32_16x16x32_bf16(af[i], bfr[j], acc[i][j], 0, 0, 0);
  }
#pragma unroll
  for (int i = 0; i < 4; ++i) {
#pragma unroll
    for (int j = 0; j < JJ; ++j) {
      int col = bn + wc * NW + j * 16 + lr;
      float bv = (EPI >= 1) ? bias[col] : 0.f;
#pragma unroll
      for (int r = 0; r < 4; ++r) {
        int row = bm + wr * 64 + i * 16 + lh * 4 + r;
        float t = acc[i][j][r] + bv;
        if (EPI == 2) t = 0.5f * t * (1.f + erff(t * 0.70710678118654752f));
        if (EPI == 3) t = fmaxf(t, 0.f) + log1pf(__expf(-fabsf(t)));
        if constexpr (sizeof(OT) == 2) C[(size_t)row * N + col] = (OT)f2bf(t);
        else                           C[(size_t)row * N + col] = (OT)t;
      }
    }
  }
}

// ---------------- x_proj via MFMA: xdbl[M,64] = ucb @ Wxb^T (+ bf16 dt_r copy) ----------------
__global__ __launch_bounds__(256) void xproj_mfma(const u16* __restrict__ A,
                                                  const u16* __restrict__ W,
                                                  float* __restrict__ C,
                                                  u16* __restrict__ bdtr)
{
  __shared__ u16 As[128][40];
  __shared__ u16 Bs[64][40];
  const int bm = blockIdx.x * 128;
  const int tid = threadIdx.x;
  const int w = tid >> 6, l = tid & 63;
  const int lr = l & 15, lh = l >> 4;
  const int sr0 = tid >> 2, sc0 = tid & 3;
  f32x4 acc[2][4] = {};
  for (int k0 = 0; k0 < DIN; k0 += 32) {
    uint4 a0 = *(const uint4*)&A[(size_t)(bm + sr0) * DIN + k0 + sc0 * 8];
    uint4 a1 = *(const uint4*)&A[(size_t)(bm + sr0 + 64) * DIN + k0 + sc0 * 8];
    uint4 b0;
    if (sr0 < 64) b0 = *(const uint4*)&W[(size_t)sr0 * DIN + k0 + sc0 * 8];
    __syncthreads();
    *(uint4*)&As[sr0][sc0 * 8] = a0;
    *(uint4*)&As[sr0 + 64][sc0 * 8] = a1;
    if (sr0 < 64) *(uint4*)&Bs[sr0][sc0 * 8] = b0;
    __syncthreads();
    bf16x8 af[2], bfr[4];
#pragma unroll
    for (int i = 0; i < 2; ++i) af[i]  = *(bf16x8*)&As[w * 32 + i * 16 + lr][lh * 8];
#pragma unroll
    for (int j = 0; j < 4; ++j) bfr[j] = *(bf16x8*)&Bs[j * 16 + lr][lh * 8];
#pragma unroll
    for (int i = 0; i < 2; ++i)
#pragma unroll
      for (int j = 0; j < 4; ++j)
        acc[i][j] = __builtin_amdgcn_mfma_f32_16x16x32_bf16(af[i], bfr[j], acc[i][j], 0, 0, 0);
  }
#pragma unroll
  for (int i = 0; i < 2; ++i)
#pragma unroll
    for (int j = 0; j < 4; ++j) {
      int col = j * 16 + lr;
#pragma unroll
      for (int r = 0; r < 4; ++r) {
        int row = bm + w * 32 + i * 16 + lh * 4 + r;
        float v = acc[i][j][r];
        C[(size_t)row * 64 + col] = v;
        if (j < 2) bdtr[(size_t)row * RNK + col] = f2bf(v);   // dt_r cols 0..31
      }
    }
}

// ---------------- depthwise causal conv (K=4) + SiLU; bf16 in (xzb), bf16 out ----------------
__global__ __launch_bounds__(256) void conv_silu(const u16* __restrict__ xzb,
                                                 const float* __restrict__ conv_w,
                                                 const float* __restrict__ conv_b,
                                                 u16* __restrict__ ucb)
{
  int idx = blockIdx.x * 256 + threadIdx.x;
  int d = idx & (DIN - 1);
  int bl = idx >> 10;
  int l = bl & (LL - 1);
  int b = bl >> 10;
  float acc = conv_b[d];
#pragma unroll
  for (int k = 0; k < 4; ++k) {
    int ls = l - 3 + k;
    float uv = (ls >= 0) ? bf2f(xzb[((size_t)(b * LL + ls)) * (2 * DIN) + d]) : 0.f;
    acc = fmaf(uv, conv_w[d * 4 + k], acc);
  }
  ucb[idx] = f2bf(siluf_(acc));
}

// ================= fused persistent scan (cooperative, 512 blocks = 2/CU) =================
// thread = one d with 16 n-states in registers; chunk data staged ONCE in LDS and
// reused across phases A (local scan) / B (global combine) / C (replay+output).
__global__ __launch_bounds__(256) void scan_fused(const float* __restrict__ dt,
                                                  const u16* __restrict__ ucb,
                                                  const u16* __restrict__ xzb,
                                                  const float* __restrict__ xdbl,
                                                  const float* __restrict__ A_log,
                                                  const float* __restrict__ D_skip,
                                                  float* __restrict__ apG,
                                                  float* __restrict__ hG,
                                                  u16* __restrict__ ygb)
{
  __shared__ float dts[CT][256];   // 16 KB
  __shared__ float us[CT][256];    // 16 KB
  __shared__ float zs[CT][256];    // 16 KB
  __shared__ float Bs[CT][NS];
  __shared__ float Cs[CT][NS];
  const int d0 = blockIdx.x * 256, c = blockIdx.y, b = blockIdx.z;
  const int tid = threadIdx.x;
  const int t0 = c * CT;
  // ---- stage chunk once ----
  for (int i = tid; i < CT * 64; i += 256) {
    int r = i >> 6, col = (i & 63) * 4;
    size_t row = (size_t)(b * LL + t0 + r);
    *(float4*)&dts[r][col] = *(const float4*)&dt[row * DIN + d0 + col];
    ushort4 uv = *(const ushort4*)&ucb[row * DIN + d0 + col];
    float4 uf = { bf2f(uv.x), bf2f(uv.y), bf2f(uv.z), bf2f(uv.w) };
    *(float4*)&us[r][col] = uf;
    ushort4 zv = *(const ushort4*)&xzb[row * (2 * DIN) + DIN + d0 + col];
    float4 zf = { bf2f(zv.x), bf2f(zv.y), bf2f(zv.z), bf2f(zv.w) };
    *(float4*)&zs[r][col] = zf;
  }
  { int r = tid >> 4, n = tid & 15;
    size_t row = (size_t)(b * LL + t0 + r);
    Bs[r][n] = xdbl[row * 64 + 32 + n];
    Cs[r][n] = xdbl[row * 64 + 48 + n]; }
  __syncthreads();
  const int d = d0 + tid;
  const int bd = b * DIN + d;
  float Ad[NS];
#pragma unroll
  for (int n = 0; n < NS; ++n) Ad[n] = -__expf(A_log[d * NS + n]);
  // ---- phase A: chunk-local scan (h0=0) + decay exp(A*sum dt) ----
  {
    float h[NS] = {};
    float sdt = 0.f;
#pragma unroll 4
    for (int t = 0; t < CT; ++t) {
      float dtv = dts[t][tid];
      float dtu = dtv * us[t][tid];
      sdt += dtv;
      float4 B0 = *(float4*)&Bs[t][0],  B1 = *(float4*)&Bs[t][4];
      float4 B2 = *(float4*)&Bs[t][8],  B3 = *(float4*)&Bs[t][12];
      float Bq[NS] = { B0.x, B0.y, B0.z, B0.w, B1.x, B1.y, B1.z, B1.w,
                       B2.x, B2.y, B2.z, B2.w, B3.x, B3.y, B3.z, B3.w };
#pragma unroll
      for (int n = 0; n < NS; ++n) {
        float a = __expf(dtv * Ad[n]);
        h[n] = fmaf(a, h[n], dtu * Bq[n]);
      }
    }
#pragma unroll
    for (int n = 0; n < NS; ++n) {
      apG[((size_t)c * NS + n) * BDIN + bd] = __expf(Ad[n] * sdt);
      hG [((size_t)c * NS + n) * BDIN + bd] = h[n];
    }
  }
  cg::this_grid().sync();
  // ---- phase B: exclusive combine over chunks (32768 chains on 1/4 of threads) ----
  {
    const int gl = ((blockIdx.z * gridDim.y + blockIdx.y) * gridDim.x + blockIdx.x) * 256 + tid;
    if (gl < NS * BDIN) {
      float H = 0.f;
#pragma unroll 16
      for (int c2 = 0; c2 < NC; ++c2) {
        size_t o = (size_t)c2 * (NS * BDIN) + gl;
        float ap = apG[o];
        float hl = hG[o];
        hG[o] = H;
        H = fmaf(ap, H, hl);
      }
    }
  }
  cg::this_grid().sync();
  // ---- phase C: replay from hinit using LDS-resident chunk, fused D_skip + silu(z) ----
  {
    const float Dd = D_skip[d];
    float h[NS];
#pragma unroll
    for (int n = 0; n < NS; ++n) h[n] = hG[((size_t)c * NS + n) * BDIN + bd];
#pragma unroll 2
    for (int t = 0; t < CT; ++t) {
      float dtv = dts[t][tid];
      float ucv = us[t][tid];
      float dtu = dtv * ucv;
      float4 B0 = *(float4*)&Bs[t][0],  B1 = *(float4*)&Bs[t][4];
      float4 B2 = *(float4*)&Bs[t][8],  B3 = *(float4*)&Bs[t][12];
      float4 C0 = *(float4*)&Cs[t][0],  C1 = *(float4*)&Cs[t][4];
      float4 C2 = *(float4*)&Cs[t][8],  C3 = *(float4*)&Cs[t][12];
      float Bq[NS] = { B0.x, B0.y, B0.z, B0.w, B1.x, B1.y, B1.z, B1.w,
                       B2.x, B2.y, B2.z, B2.w, B3.x, B3.y, B3.z, B3.w };
      float Cq[NS] = { C0.x, C0.y, C0.z, C0.w, C1.x, C1.y, C1.z, C1.w,
                       C2.x, C2.y, C2.z, C2.w, C3.x, C3.y, C3.z, C3.w };
      float y = 0.f;
#pragma unroll
      for (int n = 0; n < NS; ++n) {
        float a = __expf(dtv * Ad[n]);
        h[n] = fmaf(a, h[n], dtu * Bq[n]);
        y = fmaf(h[n], Cq[n], y);
      }
      float o = fmaf(ucv, Dd, y) * siluf_(zs[t][tid]);
      ygb[(size_t)(b * LL + t0 + t) * DIN + d0 + tid] = f2bf(o);
    }
  }
}

// ---------------- LN1: r = layernorm(x - m)*g1 + b1, dual fp32+bf16 out ----------------
__global__ __launch_bounds__(256) void ln1_kernel(const float* __restrict__ x,
                                                  const float* __restrict__ m,
                                                  const float* __restrict__ g,
                                                  const float* __restrict__ b,
                                                  float* __restrict__ r,
                                                  u16* __restrict__ rbf)
{
  int row = blockIdx.x;
  int tid = threadIdx.x;
  size_t base = (size_t)row * DD;
  float2 xv = *(const float2*)&x[base + tid * 2];
  float2 mv = *(const float2*)&m[base + tid * 2];
  float v0 = xv.x - mv.x, v1 = xv.y - mv.y;
  float s = v0 + v1, ss = v0 * v0 + v1 * v1;
#pragma unroll
  for (int off = 32; off; off >>= 1) { s += __shfl_down(s, off, 64); ss += __shfl_down(ss, off, 64); }
  __shared__ float sm[8];
  int w = tid >> 6;
  if ((tid & 63) == 0) { sm[w] = s; sm[4 + w] = ss; }
  __syncthreads();
  float S = sm[0] + sm[1] + sm[2] + sm[3];
  float SS = sm[4] + sm[5] + sm[6] + sm[7];
  float mean = S * (1.f / DD);
  float var = SS * (1.f / DD) - mean * mean;
  float rstd = rsqrtf(var + 1e-5f);
  float2 gv = *(const float2*)&g[tid * 2];
  float2 bv = *(const float2*)&b[tid * 2];
  float2 o;
  o.x = (v0 - mean) * rstd * gv.x + bv.x;
  o.y = (v1 - mean) * rstd * gv.y + bv.y;
  *(float2*)&r[base + tid * 2] = o;
  u32 pk = (u32)f2bf(o.x) | ((u32)f2bf(o.y) << 16);
  *(u32*)&rbf[base + tid * 2] = pk;
}

// ---------------- final: out = layernorm(silu(r - ff)) * g2 + b2 + x ----------------
__global__ __launch_bounds__(256) void final_kernel(const float* __restrict__ r,
                                                    const float* __restrict__ ff,
                                                    const float* __restrict__ x,
                                                    const float* __restrict__ g,
                                                    const float* __restrict__ b,
                                                    float* __restrict__ out)
{
  int row = blockIdx.x;
  int tid = threadIdx.x;
  size_t base = (size_t)row * DD;
  float2 rv = *(const float2*)&r[base + tid * 2];
  float2 fv = *(const float2*)&ff[base + tid * 2];
  float v0 = rv.x - fv.x, v1 = rv.y - fv.y;
  v0 = siluf_(v0); v1 = siluf_(v1);
  float s = v0 + v1, ss = v0 * v0 + v1 * v1;
#pragma unroll
  for (int off = 32; off; off >>= 1) { s += __shfl_down(s, off, 64); ss += __shfl_down(ss, off, 64); }
  __shared__ float sm[8];
  int w = tid >> 6;
  if ((tid & 63) == 0) { sm[w] = s; sm[4 + w] = ss; }
  __syncthreads();
  float S = sm[0] + sm[1] + sm[2] + sm[3];
  float SS = sm[4] + sm[5] + sm[6] + sm[7];
  float mean = S * (1.f / DD);
  float var = SS * (1.f / DD) - mean * mean;
  float rstd = rsqrtf(var + 1e-5f);
  float2 gv = *(const float2*)&g[tid * 2];
  float2 bv = *(const float2*)&b[tid * 2];
  float2 xv = *(const float2*)&x[base + tid * 2];
  float2 o;
  o.x = (v0 - mean) * rstd * gv.x + bv.x + xv.x;
  o.y = (v1 - mean) * rstd * gv.y + bv.y + xv.y;
  *(float2*)&out[base + tid * 2] = o;
}

extern "C" void kernel_launch(void* const* d_in, const int* in_sizes, int n_in,
                              void* d_out, int out_size, void* d_ws, size_t ws_size,
                              hipStream_t stream)
{
  const float* x      = (const float*)d_in[0];
  const float* W_in   = (const float*)d_in[1];
  const float* conv_w = (const float*)d_in[2];
  const float* conv_b = (const float*)d_in[3];
  const float* W_xp   = (const float*)d_in[4];
  const float* W_dt   = (const float*)d_in[5];
  const float* b_dt   = (const float*)d_in[6];
  const float* A_log  = (const float*)d_in[7];
  const float* D_skip = (const float*)d_in[8];
  const float* W_out  = (const float*)d_in[9];
  const float* g1     = (const float*)d_in[10];
  const float* b1     = (const float*)d_in[11];
  const float* W_ff1  = (const float*)d_in[12];
  const float* b_ff1  = (const float*)d_in[13];
  const float* W_ff2  = (const float*)d_in[14];
  const float* b_ff2  = (const float*)d_in[15];
  const float* g2     = (const float*)d_in[16];
  const float* b2     = (const float*)d_in[17];
  float* out = (float*)d_out;

  // linear layout, ~71 MB total
  float* ws = (float*)d_ws;
  u16*   xzb    = (u16*)ws;                 // 4,194,304 u16 (in slot of 4M floats)
  float* xdbl   = ws + 4194304;             //   131,072
  float* dtb    = ws + 4325376;             // 2,097,152
  float* apG    = ws + 6422528;             // 2,097,152
  float* hG     = ws + 8519680;             // 2,097,152
  float* mb     = ws + 10616832;            // 1,048,576
  float* rb     = ws + 11665408;            // 1,048,576
  u16*   bffh   = (u16*)(ws + 12713984);    // 2,097,152 u16
  u16*   ygb    = (u16*)(ws + 13762560);    // 2,097,152 u16
  u16*   ucb    = (u16*)(ws + 14811136);    // 2,097,152 u16
  u16*   brb    = (u16*)(ws + 15859712);    // 1,048,576 u16
  u16*   bdtr   = (u16*)(ws + 16384000);    //    65,536 u16
  u16*   bx     = (u16*)(ws + 16416768);    // 1,048,576 u16
  u16*   bW_in  = (u16*)(ws + 16941056);    // 1,048,576 u16
  u16*   bWxp   = (u16*)(ws + 17989632);    //    65,536 u16
  u16*   bW_dt  = (u16*)(ws + 18022400);    //    32,768 u16
  u16*   bW_out = (u16*)(ws + 18038784);    //   524,288 u16
  u16*   bW_ff1 = (u16*)(ws + 18300928);    //   524,288 u16
  u16*   bW_ff2 = (u16*)(ws + 18563072);    //   524,288 u16

  // 1. fused casts (x + 6 weights)
  cast_all<<<1840, 256, 0, stream>>>(x, W_in, W_xp, W_dt, W_out, W_ff1, W_ff2,
                                     bx, bW_in, bWxp, bW_dt, bW_out, bW_ff1, bW_ff2);
  // 2. in_proj -> bf16 xz   (BM=128, BN=64 -> 512 blocks, 2/CU)
  gemm_t<128, 64, 0, u16><<<dim3(2 * DIN / 64, ML / 128), 256, 0, stream>>>(
      bx, bW_in, nullptr, xzb, ML, 2 * DIN, DD);
  // 3. conv + silu -> ucb (bf16)
  conv_silu<<<(ML * DIN) / 256, 256, 0, stream>>>(xzb, conv_w, conv_b, ucb);
  // 4. x_proj (bf16 MFMA), also emits bf16 dt_r
  xproj_mfma<<<ML / 128, 256, 0, stream>>>(ucb, bWxp, xdbl, bdtr);
  // 5. dt_proj as MFMA GEMM + softplus epilogue
  gemm_t<128, 64, 3, float><<<dim3(DIN / 64, ML / 128), 256, 0, stream>>>(
      bdtr, bW_dt, b_dt, dtb, ML, DIN, RNK);
  // 6. fused persistent scan (cooperative; 512 blocks, 50 KB LDS -> exactly 2/CU)
  {
    void* args[] = { (void*)&dtb, (void*)&ucb, (void*)&xzb, (void*)&xdbl, (void*)&A_log,
                     (void*)&D_skip, (void*)&apG, (void*)&hG, (void*)&ygb };
    hipLaunchCooperativeKernel((const void*)scan_fused, dim3(DIN / 256, NC, BB),
                               dim3(256), args, 0, stream);
  }
  // 7. out_proj: mb = yg @ W_out^T  (BM=64, BN=64 -> 256 blocks)
  gemm_t<64, 64, 0, float><<<dim3(DD / 64, ML / 64), 256, 0, stream>>>(
      ygb, bW_out, nullptr, mb, ML, DD, DIN);
  // 8. LN1 (fp32 + bf16 out)
  ln1_kernel<<<ML, 256, 0, stream>>>(x, mb, g1, b1, rb, brb);
  // 9. ff1 + bias + gelu -> bf16  (BM=128, BN=64 -> 256 blocks)
  gemm_t<128, 64, 2, u16><<<dim3(DIN / 64, ML / 128), 256, 0, stream>>>(
      brb, bW_ff1, b_ff1, bffh, ML, DIN, DD);
  // 10. ff2 + bias -> mb  (BM=64, BN=64 -> 256 blocks)
  gemm_t<64, 64, 1, float><<<dim3(DD / 64, ML / 64), 256, 0, stream>>>(
      bffh, bW_ff2, b_ff2, mb, ML, DD, DIN);
  // 11. final
  final_kernel<<<ML, 256, 0, stream>>>(rb, mb, x, g2, b2, out);
}

// Round 10
// 174.004 us; speedup vs baseline: 1.6438x; 1.6438x over previous
//
#include <hip/hip_runtime.h>
#include <math.h>

#define BB 2
#define LL 1024
#define DD 512
#define DIN 1024      // d_inner
#define NS 16         // d_state
#define RNK 32        // dt_rank
#define ML (BB*LL)    // 2048 rows
#define CT 16         // scan chunk length
#define NC (LL/CT)    // 64 chunks
#define BDIN (BB*DIN) // 2048

typedef unsigned short u16;
typedef unsigned int u32;

__device__ __forceinline__ float sigmoidf_(float v) { return 1.f / (1.f + __expf(-v)); }
__device__ __forceinline__ float siluf_(float v) { return v * sigmoidf_(v); }
__device__ __forceinline__ u16 f2bf(float f) {
  union { float f; u32 u; } c; c.f = f;
  u32 r = c.u + 0x7fffu + ((c.u >> 16) & 1u);
  return (u16)(r >> 16);
}
__device__ __forceinline__ float bf2f(u16 x) {
  union { u32 u; float f; } c; c.u = (u32)x << 16;
  return c.f;
}

// ---------------- fused bf16 cast of x + all weights (one launch) ----------------
// 2048 elems/block: x 512 | W_in 512 | W_xp 32 | W_dt 16 | W_out 256 | W_ff1 256 | W_ff2 256
__global__ __launch_bounds__(256) void cast_all(const float* __restrict__ x,
                                                const float* __restrict__ Wi,
                                                const float* __restrict__ Wx,
                                                const float* __restrict__ Wd,
                                                const float* __restrict__ Wo,
                                                const float* __restrict__ Wf1,
                                                const float* __restrict__ Wf2,
                                                u16* bx, u16* bWi, u16* bWx, u16* bWd,
                                                u16* bWo, u16* bWf1, u16* bWf2)
{
  int bid = blockIdx.x;
  const float* src; u16* dst; int base;
  if (bid < 512)       { src = x;   dst = bx;   base = 0; }
  else if (bid < 1024) { src = Wi;  dst = bWi;  base = 512; }
  else if (bid < 1056) { src = Wx;  dst = bWx;  base = 1024; }
  else if (bid < 1072) { src = Wd;  dst = bWd;  base = 1056; }
  else if (bid < 1328) { src = Wo;  dst = bWo;  base = 1072; }
  else if (bid < 1584) { src = Wf1; dst = bWf1; base = 1328; }
  else                 { src = Wf2; dst = bWf2; base = 1584; }
  int i = ((bid - base) * 256 + threadIdx.x) * 8;
  float4 v0 = *(const float4*)&src[i];
  float4 v1 = *(const float4*)&src[i + 4];
  union { u16 u[8]; uint4 v; } p;
  p.u[0] = f2bf(v0.x); p.u[1] = f2bf(v0.y); p.u[2] = f2bf(v0.z); p.u[3] = f2bf(v0.w);
  p.u[4] = f2bf(v1.x); p.u[5] = f2bf(v1.y); p.u[6] = f2bf(v1.z); p.u[7] = f2bf(v1.w);
  *(uint4*)&dst[i] = p.v;
}

// ---------------- tiled bf16 MFMA GEMM: C[M,N] = A[M,K] @ W[N,K]^T ----------------
// EPI: 0 none, 1 +bias, 2 +bias+gelu, 3 +bias+softplus.  OT: float or u16
using bf16x8 = __attribute__((ext_vector_type(8))) short;
using f32x4  = __attribute__((ext_vector_type(4))) float;

template<int BM, int BN, int EPI, typename OT>
__global__ __launch_bounds__(256) void gemm_t(const u16* __restrict__ A,
                                              const u16* __restrict__ W,
                                              const float* __restrict__ bias,
                                              OT* __restrict__ C,
                                              int M, int N, int K)
{
  constexpr int WR = BM / 64;
  constexpr int WC = 4 / WR;
  constexpr int NW = BN / WC;       // cols per wave
  constexpr int JJ = NW / 16;       // 16-col fragments per wave
  constexpr int RB = BN / 64;       // B row-groups for staging
  __shared__ u16 As[BM][40];        // pad to 40 (80B row): 2-way bank alias = free
  __shared__ u16 Bs[BN][40];
  const int bm = blockIdx.y * BM, bn = blockIdx.x * BN;
  const int tid = threadIdx.x;
  const int w = tid >> 6, l = tid & 63;
  const int wr = w / WC, wc = w % WC;
  const int lr = l & 15, lh = l >> 4;
  const int sr0 = tid >> 2, sc0 = tid & 3;
  f32x4 acc[4][JJ] = {};
  for (int k0 = 0; k0 < K; k0 += 32) {
    uint4 areg[WR], breg[RB];
#pragma unroll
    for (int i = 0; i < WR; ++i)
      areg[i] = *(const uint4*)&A[(size_t)(bm + sr0 + 64 * i) * K + k0 + sc0 * 8];
#pragma unroll
    for (int i = 0; i < RB; ++i)
      breg[i] = *(const uint4*)&W[(size_t)(bn + sr0 + 64 * i) * K + k0 + sc0 * 8];
    __syncthreads();
#pragma unroll
    for (int i = 0; i < WR; ++i) *(uint4*)&As[sr0 + 64 * i][sc0 * 8] = areg[i];
#pragma unroll
    for (int i = 0; i < RB; ++i) *(uint4*)&Bs[sr0 + 64 * i][sc0 * 8] = breg[i];
    __syncthreads();
    bf16x8 af[4], bfr[JJ];
#pragma unroll
    for (int i = 0; i < 4; ++i) af[i]  = *(bf16x8*)&As[wr * 64 + i * 16 + lr][lh * 8];
#pragma unroll
    for (int j = 0; j < JJ; ++j) bfr[j] = *(bf16x8*)&Bs[wc * NW + j * 16 + lr][lh * 8];
#pragma unroll
    for (int i = 0; i < 4; ++i)
#pragma unroll
      for (int j = 0; j < JJ; ++j)
        acc[i][j] = __builtin_amdgcn_mfma_f32_16x16x32_bf16(af[i], bfr[j], acc[i][j], 0, 0, 0);
  }
#pragma unroll
  for (int i = 0; i < 4; ++i) {
#pragma unroll
    for (int j = 0; j < JJ; ++j) {
      int col = bn + wc * NW + j * 16 + lr;
      float bv = (EPI >= 1) ? bias[col] : 0.f;
#pragma unroll
      for (int r = 0; r < 4; ++r) {
        int row = bm + wr * 64 + i * 16 + lh * 4 + r;
        float t = acc[i][j][r] + bv;
        if (EPI == 2) t = 0.5f * t * (1.f + erff(t * 0.70710678118654752f));
        if (EPI == 3) t = fmaxf(t, 0.f) + log1pf(__expf(-fabsf(t)));
        if constexpr (sizeof(OT) == 2) C[(size_t)row * N + col] = (OT)f2bf(t);
        else                           C[(size_t)row * N + col] = (OT)t;
      }
    }
  }
}

// ---------------- x_proj via MFMA: xdbl[M,64] = ucb @ Wxb^T (+ bf16 dt_r copy) ----------------
__global__ __launch_bounds__(256) void xproj_mfma(const u16* __restrict__ A,
                                                  const u16* __restrict__ W,
                                                  float* __restrict__ C,
                                                  u16* __restrict__ bdtr)
{
  __shared__ u16 As[128][40];
  __shared__ u16 Bs[64][40];
  const int bm = blockIdx.x * 128;
  const int tid = threadIdx.x;
  const int w = tid >> 6, l = tid & 63;
  const int lr = l & 15, lh = l >> 4;
  const int sr0 = tid >> 2, sc0 = tid & 3;
  f32x4 acc[2][4] = {};
  for (int k0 = 0; k0 < DIN; k0 += 32) {
    uint4 a0 = *(const uint4*)&A[(size_t)(bm + sr0) * DIN + k0 + sc0 * 8];
    uint4 a1 = *(const uint4*)&A[(size_t)(bm + sr0 + 64) * DIN + k0 + sc0 * 8];
    uint4 b0;
    if (sr0 < 64) b0 = *(const uint4*)&W[(size_t)sr0 * DIN + k0 + sc0 * 8];
    __syncthreads();
    *(uint4*)&As[sr0][sc0 * 8] = a0;
    *(uint4*)&As[sr0 + 64][sc0 * 8] = a1;
    if (sr0 < 64) *(uint4*)&Bs[sr0][sc0 * 8] = b0;
    __syncthreads();
    bf16x8 af[2], bfr[4];
#pragma unroll
    for (int i = 0; i < 2; ++i) af[i]  = *(bf16x8*)&As[w * 32 + i * 16 + lr][lh * 8];
#pragma unroll
    for (int j = 0; j < 4; ++j) bfr[j] = *(bf16x8*)&Bs[j * 16 + lr][lh * 8];
#pragma unroll
    for (int i = 0; i < 2; ++i)
#pragma unroll
      for (int j = 0; j < 4; ++j)
        acc[i][j] = __builtin_amdgcn_mfma_f32_16x16x32_bf16(af[i], bfr[j], acc[i][j], 0, 0, 0);
  }
#pragma unroll
  for (int i = 0; i < 2; ++i)
#pragma unroll
    for (int j = 0; j < 4; ++j) {
      int col = j * 16 + lr;
#pragma unroll
      for (int r = 0; r < 4; ++r) {
        int row = bm + w * 32 + i * 16 + lh * 4 + r;
        float v = acc[i][j][r];
        C[(size_t)row * 64 + col] = v;
        if (j < 2) bdtr[(size_t)row * RNK + col] = f2bf(v);   // dt_r cols 0..31
      }
    }
}

// ---------------- depthwise causal conv (K=4) + SiLU; bf16 in (xzb), bf16 out ----------------
__global__ __launch_bounds__(256) void conv_silu(const u16* __restrict__ xzb,
                                                 const float* __restrict__ conv_w,
                                                 const float* __restrict__ conv_b,
                                                 u16* __restrict__ ucb)
{
  int idx = blockIdx.x * 256 + threadIdx.x;
  int d = idx & (DIN - 1);
  int bl = idx >> 10;
  int l = bl & (LL - 1);
  int b = bl >> 10;
  float acc = conv_b[d];
#pragma unroll
  for (int k = 0; k < 4; ++k) {
    int ls = l - 3 + k;
    float uv = (ls >= 0) ? bf2f(xzb[((size_t)(b * LL + ls)) * (2 * DIN) + d]) : 0.f;
    acc = fmaf(uv, conv_w[d * 4 + k], acc);
  }
  ucb[idx] = f2bf(siluf_(acc));
}

// ================= chunked selective scan, register-state (3 kernels) =================
// thread = one d, 16 n-states in VGPRs. state layout: [c][n][b*DIN+d]

__global__ __launch_bounds__(256) void scan_p1(const float* __restrict__ dt,
                                               const u16* __restrict__ ucb,
                                               const float* __restrict__ xdbl,
                                               const float* __restrict__ A_log,
                                               float* __restrict__ apG,
                                               float* __restrict__ hG)
{
  __shared__ float dts[CT][256];
  __shared__ float us[CT][256];
  __shared__ float Bs[CT][NS];
  const int d0 = blockIdx.x * 256, c = blockIdx.y, b = blockIdx.z;
  const int tid = threadIdx.x;
  const int t0 = c * CT;
  for (int i = tid; i < CT * 64; i += 256) {
    int r = i >> 6, col = (i & 63) * 4;
    size_t row = (size_t)(b * LL + t0 + r);
    *(float4*)&dts[r][col] = *(const float4*)&dt[row * DIN + d0 + col];
    ushort4 uv = *(const ushort4*)&ucb[row * DIN + d0 + col];
    float4 uf = { bf2f(uv.x), bf2f(uv.y), bf2f(uv.z), bf2f(uv.w) };
    *(float4*)&us[r][col] = uf;
  }
  { int r = tid >> 4, n = tid & 15;
    Bs[r][n] = xdbl[(size_t)(b * LL + t0 + r) * 64 + 32 + n]; }
  __syncthreads();
  const int d = d0 + tid;
  float Ad[NS];
#pragma unroll
  for (int n = 0; n < NS; ++n) Ad[n] = -__expf(A_log[d * NS + n]);
  float h[NS] = {};
  float sdt = 0.f;
#pragma unroll 4
  for (int t = 0; t < CT; ++t) {
    float dtv = dts[t][tid];
    float dtu = dtv * us[t][tid];
    sdt += dtv;
    float4 B0 = *(float4*)&Bs[t][0],  B1 = *(float4*)&Bs[t][4];
    float4 B2 = *(float4*)&Bs[t][8],  B3 = *(float4*)&Bs[t][12];
    float Bq[NS] = { B0.x, B0.y, B0.z, B0.w, B1.x, B1.y, B1.z, B1.w,
                     B2.x, B2.y, B2.z, B2.w, B3.x, B3.y, B3.z, B3.w };
#pragma unroll
    for (int n = 0; n < NS; ++n) {
      float a = __expf(dtv * Ad[n]);
      h[n] = fmaf(a, h[n], dtu * Bq[n]);
    }
  }
  const int bd = b * DIN + d;
#pragma unroll
  for (int n = 0; n < NS; ++n) {
    apG[((size_t)c * NS + n) * BDIN + bd] = __expf(Ad[n] * sdt);
    hG [((size_t)c * NS + n) * BDIN + bd] = h[n];
  }
}

__global__ __launch_bounds__(128) void scan_p2(const float* __restrict__ apG,
                                               float* __restrict__ hG)
{
  const int idx = blockIdx.x * 128 + threadIdx.x;
  float H = 0.f;
#pragma unroll 16
  for (int c = 0; c < NC; ++c) {
    size_t o = (size_t)c * (NS * BDIN) + idx;
    float ap = apG[o];
    float hl = hG[o];
    hG[o] = H;
    H = fmaf(ap, H, hl);
  }
}

__global__ __launch_bounds__(256) void scan_p3(const float* __restrict__ dt,
                                               const u16* __restrict__ ucb,
                                               const u16* __restrict__ xzb,
                                               const float* __restrict__ xdbl,
                                               const float* __restrict__ A_log,
                                               const float* __restrict__ D_skip,
                                               const float* __restrict__ hG,
                                               u16* __restrict__ ygb)
{
  __shared__ float dts[CT][256];
  __shared__ float us[CT][256];
  __shared__ float zs[CT][256];
  __shared__ float Bs[CT][NS];
  __shared__ float Cs[CT][NS];
  const int d0 = blockIdx.x * 256, c = blockIdx.y, b = blockIdx.z;
  const int tid = threadIdx.x;
  const int t0 = c * CT;
  for (int i = tid; i < CT * 64; i += 256) {
    int r = i >> 6, col = (i & 63) * 4;
    size_t row = (size_t)(b * LL + t0 + r);
    *(float4*)&dts[r][col] = *(const float4*)&dt[row * DIN + d0 + col];
    ushort4 uv = *(const ushort4*)&ucb[row * DIN + d0 + col];
    float4 uf = { bf2f(uv.x), bf2f(uv.y), bf2f(uv.z), bf2f(uv.w) };
    *(float4*)&us[r][col] = uf;
    ushort4 zv = *(const ushort4*)&xzb[row * (2 * DIN) + DIN + d0 + col];
    float4 zf = { bf2f(zv.x), bf2f(zv.y), bf2f(zv.z), bf2f(zv.w) };
    *(float4*)&zs[r][col] = zf;
  }
  { int r = tid >> 4, n = tid & 15;
    size_t row = (size_t)(b * LL + t0 + r);
    Bs[r][n] = xdbl[row * 64 + 32 + n];
    Cs[r][n] = xdbl[row * 64 + 48 + n]; }
  __syncthreads();
  const int d = d0 + tid;
  const int bd = b * DIN + d;
  float Ad[NS];
#pragma unroll
  for (int n = 0; n < NS; ++n) Ad[n] = -__expf(A_log[d * NS + n]);
  const float Dd = D_skip[d];
  float h[NS];
#pragma unroll
  for (int n = 0; n < NS; ++n) h[n] = hG[((size_t)c * NS + n) * BDIN + bd];
#pragma unroll 2
  for (int t = 0; t < CT; ++t) {
    float dtv = dts[t][tid];
    float ucv = us[t][tid];
    float dtu = dtv * ucv;
    float4 B0 = *(float4*)&Bs[t][0],  B1 = *(float4*)&Bs[t][4];
    float4 B2 = *(float4*)&Bs[t][8],  B3 = *(float4*)&Bs[t][12];
    float4 C0 = *(float4*)&Cs[t][0],  C1 = *(float4*)&Cs[t][4];
    float4 C2 = *(float4*)&Cs[t][8],  C3 = *(float4*)&Cs[t][12];
    float Bq[NS] = { B0.x, B0.y, B0.z, B0.w, B1.x, B1.y, B1.z, B1.w,
                     B2.x, B2.y, B2.z, B2.w, B3.x, B3.y, B3.z, B3.w };
    float Cq[NS] = { C0.x, C0.y, C0.z, C0.w, C1.x, C1.y, C1.z, C1.w,
                     C2.x, C2.y, C2.z, C2.w, C3.x, C3.y, C3.z, C3.w };
    float y = 0.f;
#pragma unroll
    for (int n = 0; n < NS; ++n) {
      float a = __expf(dtv * Ad[n]);
      h[n] = fmaf(a, h[n], dtu * Bq[n]);
      y = fmaf(h[n], Cq[n], y);
    }
    float o = fmaf(ucv, Dd, y) * siluf_(zs[t][tid]);
    ygb[(size_t)(b * LL + t0 + t) * DIN + d0 + tid] = f2bf(o);
  }
}

// ---------------- LN1: r = layernorm(x - m)*g1 + b1, dual fp32+bf16 out ----------------
__global__ __launch_bounds__(256) void ln1_kernel(const float* __restrict__ x,
                                                  const float* __restrict__ m,
                                                  const float* __restrict__ g,
                                                  const float* __restrict__ b,
                                                  float* __restrict__ r,
                                                  u16* __restrict__ rbf)
{
  int row = blockIdx.x;
  int tid = threadIdx.x;
  size_t base = (size_t)row * DD;
  float2 xv = *(const float2*)&x[base + tid * 2];
  float2 mv = *(const float2*)&m[base + tid * 2];
  float v0 = xv.x - mv.x, v1 = xv.y - mv.y;
  float s = v0 + v1, ss = v0 * v0 + v1 * v1;
#pragma unroll
  for (int off = 32; off; off >>= 1) { s += __shfl_down(s, off, 64); ss += __shfl_down(ss, off, 64); }
  __shared__ float sm[8];
  int w = tid >> 6;
  if ((tid & 63) == 0) { sm[w] = s; sm[4 + w] = ss; }
  __syncthreads();
  float S = sm[0] + sm[1] + sm[2] + sm[3];
  float SS = sm[4] + sm[5] + sm[6] + sm[7];
  float mean = S * (1.f / DD);
  float var = SS * (1.f / DD) - mean * mean;
  float rstd = rsqrtf(var + 1e-5f);
  float2 gv = *(const float2*)&g[tid * 2];
  float2 bv = *(const float2*)&b[tid * 2];
  float2 o;
  o.x = (v0 - mean) * rstd * gv.x + bv.x;
  o.y = (v1 - mean) * rstd * gv.y + bv.y;
  *(float2*)&r[base + tid * 2] = o;
  u32 pk = (u32)f2bf(o.x) | ((u32)f2bf(o.y) << 16);
  *(u32*)&rbf[base + tid * 2] = pk;
}

// ---------------- final: out = layernorm(silu(r - ff)) * g2 + b2 + x ----------------
__global__ __launch_bounds__(256) void final_kernel(const float* __restrict__ r,
                                                    const float* __restrict__ ff,
                                                    const float* __restrict__ x,
                                                    const float* __restrict__ g,
                                                    const float* __restrict__ b,
                                                    float* __restrict__ out)
{
  int row = blockIdx.x;
  int tid = threadIdx.x;
  size_t base = (size_t)row * DD;
  float2 rv = *(const float2*)&r[base + tid * 2];
  float2 fv = *(const float2*)&ff[base + tid * 2];
  float v0 = rv.x - fv.x, v1 = rv.y - fv.y;
  v0 = siluf_(v0); v1 = siluf_(v1);
  float s = v0 + v1, ss = v0 * v0 + v1 * v1;
#pragma unroll
  for (int off = 32; off; off >>= 1) { s += __shfl_down(s, off, 64); ss += __shfl_down(ss, off, 64); }
  __shared__ float sm[8];
  int w = tid >> 6;
  if ((tid & 63) == 0) { sm[w] = s; sm[4 + w] = ss; }
  __syncthreads();
  float S = sm[0] + sm[1] + sm[2] + sm[3];
  float SS = sm[4] + sm[5] + sm[6] + sm[7];
  float mean = S * (1.f / DD);
  float var = SS * (1.f / DD) - mean * mean;
  float rstd = rsqrtf(var + 1e-5f);
  float2 gv = *(const float2*)&g[tid * 2];
  float2 bv = *(const float2*)&b[tid * 2];
  float2 xv = *(const float2*)&x[base + tid * 2];
  float2 o;
  o.x = (v0 - mean) * rstd * gv.x + bv.x + xv.x;
  o.y = (v1 - mean) * rstd * gv.y + bv.y + xv.y;
  *(float2*)&out[base + tid * 2] = o;
}

extern "C" void kernel_launch(void* const* d_in, const int* in_sizes, int n_in,
                              void* d_out, int out_size, void* d_ws, size_t ws_size,
                              hipStream_t stream)
{
  const float* x      = (const float*)d_in[0];
  const float* W_in   = (const float*)d_in[1];
  const float* conv_w = (const float*)d_in[2];
  const float* conv_b = (const float*)d_in[3];
  const float* W_xp   = (const float*)d_in[4];
  const float* W_dt   = (const float*)d_in[5];
  const float* b_dt   = (const float*)d_in[6];
  const float* A_log  = (const float*)d_in[7];
  const float* D_skip = (const float*)d_in[8];
  const float* W_out  = (const float*)d_in[9];
  const float* g1     = (const float*)d_in[10];
  const float* b1     = (const float*)d_in[11];
  const float* W_ff1  = (const float*)d_in[12];
  const float* b_ff1  = (const float*)d_in[13];
  const float* W_ff2  = (const float*)d_in[14];
  const float* b_ff2  = (const float*)d_in[15];
  const float* g2     = (const float*)d_in[16];
  const float* b2     = (const float*)d_in[17];
  float* out = (float*)d_out;

  // linear layout, ~71 MB total
  float* ws = (float*)d_ws;
  u16*   xzb    = (u16*)ws;                 // 4,194,304 u16
  float* xdbl   = ws + 4194304;             //   131,072
  float* dtb    = ws + 4325376;             // 2,097,152
  float* apG    = ws + 6422528;             // 2,097,152
  float* hG     = ws + 8519680;             // 2,097,152
  float* mb     = ws + 10616832;            // 1,048,576
  float* rb     = ws + 11665408;            // 1,048,576
  u16*   bffh   = (u16*)(ws + 12713984);    // 2,097,152 u16
  u16*   ygb    = (u16*)(ws + 13762560);    // 2,097,152 u16
  u16*   ucb    = (u16*)(ws + 14811136);    // 2,097,152 u16
  u16*   brb    = (u16*)(ws + 15859712);    // 1,048,576 u16
  u16*   bdtr   = (u16*)(ws + 16384000);    //    65,536 u16
  u16*   bx     = (u16*)(ws + 16416768);    // 1,048,576 u16
  u16*   bW_in  = (u16*)(ws + 16941056);    // 1,048,576 u16
  u16*   bWxp   = (u16*)(ws + 17989632);    //    65,536 u16
  u16*   bW_dt  = (u16*)(ws + 18022400);    //    32,768 u16
  u16*   bW_out = (u16*)(ws + 18038784);    //   524,288 u16
  u16*   bW_ff1 = (u16*)(ws + 18300928);    //   524,288 u16
  u16*   bW_ff2 = (u16*)(ws + 18563072);    //   524,288 u16

  // 1. fused casts (x + 6 weights)
  cast_all<<<1840, 256, 0, stream>>>(x, W_in, W_xp, W_dt, W_out, W_ff1, W_ff2,
                                     bx, bW_in, bWxp, bW_dt, bW_out, bW_ff1, bW_ff2);
  // 2. in_proj -> bf16 xz   (BM=128, BN=64 -> 512 blocks, 2/CU)
  gemm_t<128, 64, 0, u16><<<dim3(2 * DIN / 64, ML / 128), 256, 0, stream>>>(
      bx, bW_in, nullptr, xzb, ML, 2 * DIN, DD);
  // 3. conv + silu -> ucb (bf16)
  conv_silu<<<(ML * DIN) / 256, 256, 0, stream>>>(xzb, conv_w, conv_b, ucb);
  // 4. x_proj (bf16 MFMA), also emits bf16 dt_r
  xproj_mfma<<<ML / 128, 256, 0, stream>>>(ucb, bWxp, xdbl, bdtr);
  // 5. dt_proj as MFMA GEMM + softplus epilogue
  gemm_t<128, 64, 3, float><<<dim3(DIN / 64, ML / 128), 256, 0, stream>>>(
      bdtr, bW_dt, b_dt, dtb, ML, DIN, RNK);
  // 6. chunked scan (3 kernels — cooperative grid.sync cost ~55µs/sync on 8-XCD, not worth it)
  scan_p1<<<dim3(DIN / 256, NC, BB), 256, 0, stream>>>(dtb, ucb, xdbl, A_log, apG, hG);
  scan_p2<<<(NS * BDIN) / 128, 128, 0, stream>>>(apG, hG);
  scan_p3<<<dim3(DIN / 256, NC, BB), 256, 0, stream>>>(dtb, ucb, xzb, xdbl, A_log, D_skip,
                                                       hG, ygb);
  // 7. out_proj: mb = yg @ W_out^T  (BM=64, BN=64 -> 256 blocks)
  gemm_t<64, 64, 0, float><<<dim3(DD / 64, ML / 64), 256, 0, stream>>>(
      ygb, bW_out, nullptr, mb, ML, DD, DIN);
  // 8. LN1 (fp32 + bf16 out)
  ln1_kernel<<<ML, 256, 0, stream>>>(x, mb, g1, b1, rb, brb);
  // 9. ff1 + bias + gelu -> bf16  (BM=128, BN=64 -> 256 blocks)
  gemm_t<128, 64, 2, u16><<<dim3(DIN / 64, ML / 128), 256, 0, stream>>>(
      brb, bW_ff1, b_ff1, bffh, ML, DIN, DD);
  // 10. ff2 + bias -> mb  (BM=64, BN=64 -> 256 blocks)
  gemm_t<64, 64, 1, float><<<dim3(DD / 64, ML / 64), 256, 0, stream>>>(
      bffh, bW_ff2, b_ff2, mb, ML, DD, DIN);
  // 11. final
  final_kernel<<<ML, 256, 0, stream>>>(rb, mb, x, g2, b2, out);
}